// Round 11
// baseline (124.104 us; speedup 1.0000x reference)
//
#include <hip/hip_runtime.h>
#include <hip/hip_bf16.h>
#include <math.h>

#define BDIM 32
#define TDIM 1025
#define DDIM 768
#define GRIDW 32
#define TPATCH 1024
#define SCALE 8.0f
#define EPSLN 1e-5f
#define NROW (BDIM * TDIM)   // 32800
#define VTLD 1088            // vT row stride (elements, 16B-aligned)
#define LDP  72              // LDS row stride for attn tiles
#define BKC  256             // qkv B k-chunk
#define LDB  264             // Bs row stride (elems): 2-way bank alias = free
#define NTILES 17

typedef __attribute__((ext_vector_type(8))) short short8v;   // 8 bf16 (4 VGPRs)
typedef __attribute__((ext_vector_type(4))) float f32x4;     // MFMA C/D frag

__device__ __forceinline__ unsigned short f2bf(float f) {
    unsigned int u = __float_as_uint(f);
    u += 0x7FFFu + ((u >> 16) & 1u);      // round-to-nearest-even
    return (unsigned short)(u >> 16);
}

__device__ __forceinline__ short8v pack8(float4 a, float4 b) {
    union { short8v v; unsigned short s[8]; } u;
    u.s[0] = f2bf(a.x); u.s[1] = f2bf(a.y); u.s[2] = f2bf(a.z); u.s[3] = f2bf(a.w);
    u.s[4] = f2bf(b.x); u.s[5] = f2bf(b.y); u.s[6] = f2bf(b.z); u.s[7] = f2bf(b.w);
    return u.v;
}

// Workgroup barrier WITHOUT the vmcnt(0) drain __syncthreads() imposes.
__device__ __forceinline__ void wg_barrier() {
    asm volatile("s_waitcnt lgkmcnt(0)" ::: "memory");
    __builtin_amdgcn_s_barrier();
    __builtin_amdgcn_sched_barrier(0);
}

// ---- 16-lane (DPP-row) reductions on the VALU pipe ----
template<int CTRL>
__device__ __forceinline__ float dpp_f(float x) {
    return __int_as_float(__builtin_amdgcn_update_dpp(
        __float_as_int(x), __float_as_int(x), CTRL, 0xF, 0xF, true));
}
__device__ __forceinline__ float red16_max(float x) {
    x = fmaxf(x, dpp_f<0xB1>(x));
    x = fmaxf(x, dpp_f<0x4E>(x));
    x = fmaxf(x, dpp_f<0x124>(x));
    x = fmaxf(x, dpp_f<0x128>(x));
    return x;
}
__device__ __forceinline__ float red16_sum(float x) {
    x += dpp_f<0xB1>(x);
    x += dpp_f<0x4E>(x);
    x += dpp_f<0x124>(x);
    x += dpp_f<0x128>(x);
    return x;
}

// ---------------------------------------------------------------------------
// Kernel 0: W -> bf16, transposed: wT[c][k], c = 0..191 (q|k|v), k = 0..767
// ---------------------------------------------------------------------------
__global__ __launch_bounds__(256) void prep_w_kernel(
    const float* __restrict__ Wq, const float* __restrict__ Wk,
    const float* __restrict__ Wv, unsigned short* __restrict__ wT)
{
    const int c = blockIdx.x;
    const float* W = (c < 64) ? Wq : (c < 128) ? Wk : Wv;
    const int cc = c & 63;
    for (int k = threadIdx.x; k < DDIM; k += 256)
        wT[(size_t)c * DDIM + k] = f2bf(W[(size_t)k * 64 + cc]);
}

// ---------------------------------------------------------------------------
// Kernel 1: B-STATIONARY MFMA QKV projection + fused LN + heads.
// 513 blocks x 256 thr (4 waves x 16 rows). B in LDS for the whole kernel as
// 3 k-chunks of 256 (101 KB); A streams global->reg->bf16->MFMA directly
// (distance-2 prefetch, no A-LDS, no staging-store waits). Only 6 barriers.
// ---------------------------------------------------------------------------
__global__ __launch_bounds__(256) void qkv_bstat_kernel(
    const float* __restrict__ x, const unsigned short* __restrict__ wT,
    const float* __restrict__ gq, const float* __restrict__ bq,
    const float* __restrict__ gk, const float* __restrict__ bk,
    const float* __restrict__ Wsig, const float* __restrict__ bsig,
    const float* __restrict__ Wa, const float* __restrict__ ba,
    unsigned short* __restrict__ qb, unsigned short* __restrict__ kb,
    unsigned short* __restrict__ vb,
    float* __restrict__ a8, float* __restrict__ isx, float* __restrict__ isy)
{
    __shared__ unsigned short Bs[192][LDB];   // 101.4 KB

    const int t  = threadIdx.x;
    const int wv = t >> 6;
    const int ln = t & 63;
    const int lq = ln >> 4;
    const int lr = ln & 15;
    const int tokb = blockIdx.x * 64 + wv * 16;   // wave's first row (flat)

    // A fragment source: lane reads its own MFMA-A row directly from x
    const float* xrow = x + (size_t)min(tokb + lr, NROW - 1) * DDIM + lq * 8;

    f32x4 acc[12];
#pragma unroll
    for (int ni = 0; ni < 12; ++ni) acc[ni] = (f32x4){0.f, 0.f, 0.f, 0.f};

    // distance-2 A pipeline (steps s: k = s*32)
    float4 a00, a01, a10, a11;
    a00 = *(const float4*)(xrow + 0);
    a01 = *(const float4*)(xrow + 4);
    a10 = *(const float4*)(xrow + 32);
    a11 = *(const float4*)(xrow + 36);

#pragma unroll
    for (int kc = 0; kc < 3; ++kc) {
        // ---- stage B chunk kc: 192 rows x 256 k (cooperative, coalesced) ----
#pragma unroll
        for (int j = 0; j < 24; ++j) {
            int idx = t + 256 * j;
            int row = idx >> 5;
            int seg = idx & 31;
            short8v v = *(const short8v*)&wT[(size_t)row * DDIM + kc * BKC + seg * 8];
            *(short8v*)&Bs[row][seg * 8] = v;
        }
        wg_barrier();

#pragma unroll
        for (int ks = 0; ks < 8; ++ks) {
            const int s = kc * 8 + ks;
            float4 n0, n1;
            const bool pf = (s + 2 < 24);
            if (pf) {
                n0 = *(const float4*)(xrow + (s + 2) * 32);
                n1 = *(const float4*)(xrow + (s + 2) * 32 + 4);
            }
            short8v af = pack8(a00, a01);
#pragma unroll
            for (int ni = 0; ni < 12; ++ni) {
                short8v bf = *(const short8v*)&Bs[16 * ni + lr][ks * 32 + lq * 8];
                acc[ni] = __builtin_amdgcn_mfma_f32_16x16x32_bf16(af, bf, acc[ni], 0, 0, 0);
            }
            a00 = a10; a01 = a11;
            if (pf) { a10 = n0; a11 = n1; }
        }
        wg_barrier();   // all waves done reading Bs before next restage
    }

    // ---- epilogue: LN(q), LN(k), alpha/sigma head, writes (1 m-frag) ----
    float gqv[4], bqv[4], gkv[4], bkv[4], wav[4], ws0[4], ws1[4];
#pragma unroll
    for (int ni = 0; ni < 4; ++ni) {
        int c = lr + 16 * ni;
        gqv[ni] = gq[c]; bqv[ni] = bq[c];
        gkv[ni] = gk[c]; bkv[ni] = bk[c];
        wav[ni] = Wa[c];
        ws0[ni] = Wsig[2 * c];
        ws1[ni] = Wsig[2 * c + 1];
    }
    const float ba0 = ba[0], bs0c = bsig[0], bs1c = bsig[1];

#pragma unroll
    for (int reg = 0; reg < 4; ++reg) {
        const int tokr = tokb + lq * 4 + reg;

        float s1 = 0.f, s2 = 0.f;
#pragma unroll
        for (int ni = 0; ni < 4; ++ni) {
            float v = acc[ni][reg];
            s1 += v; s2 += v * v;
        }
        s1 = red16_sum(s1);
        s2 = red16_sum(s2);
        float mean = s1 * (1.f / 64.f);
        float var  = s2 * (1.f / 64.f) - mean * mean;
        float rstd = rsqrtf(var + EPSLN);
        float qn[4];
#pragma unroll
        for (int ni = 0; ni < 4; ++ni)
            qn[ni] = (acc[ni][reg] - mean) * rstd * gqv[ni] + bqv[ni];

        s1 = 0.f; s2 = 0.f;
#pragma unroll
        for (int ni = 0; ni < 4; ++ni) {
            float v = acc[4 + ni][reg];
            s1 += v; s2 += v * v;
        }
        s1 = red16_sum(s1);
        s2 = red16_sum(s2);
        mean = s1 * (1.f / 64.f);
        var  = s2 * (1.f / 64.f) - mean * mean;
        rstd = rsqrtf(var + EPSLN);
        float kn[4];
#pragma unroll
        for (int ni = 0; ni < 4; ++ni)
            kn[ni] = (acc[4 + ni][reg] - mean) * rstd * gkv[ni] + bkv[ni];

        float da = 0.f, d0 = 0.f, d1 = 0.f;
#pragma unroll
        for (int ni = 0; ni < 4; ++ni) {
            da += qn[ni] * wav[ni];
            d0 += qn[ni] * ws0[ni];
            d1 += qn[ni] * ws1[ni];
        }
        da = red16_sum(da);
        d0 = red16_sum(d0);
        d1 = red16_sum(d1);

        if (tokr < NROW) {
            size_t base = (size_t)tokr * 64;
            int bidx = tokr / TDIM;
            int ti   = tokr - bidx * TDIM;
#pragma unroll
            for (int ni = 0; ni < 4; ++ni) {
                int c = lr + 16 * ni;
                qb[base + c] = f2bf(qn[ni]);
                kb[base + c] = f2bf(kn[ni]);
                vb[base + c] = f2bf(acc[8 + ni][reg]);
            }
            if (lr == 0 && ti >= 1) {
                int p = bidx * TPATCH + ti - 1;
                float av = da + ba0;
                float sp = (av > 20.f) ? av : log1pf(__expf(av));
                a8[p] = sp * (1.f / SCALE);
                float sx = 1.f / (1.f + __expf(-(d0 + bs0c)));
                float sy = 1.f / (1.f + __expf(-(d1 + bs1c)));
                isx[p] = 0.5f / (sx * sx);
                isy[p] = 0.5f / (sy * sy);
            }
        }
    }
}

// ---------------------------------------------------------------------------
// Kernel 1b: vb [token][dh] -> vT [b][dh][token] via LDS transpose.
// ---------------------------------------------------------------------------
__global__ __launch_bounds__(256) void vtrans_kernel(
    const unsigned short* __restrict__ vb, unsigned short* __restrict__ vT)
{
    __shared__ unsigned short tile[64][LDP];   // [dh][token]
    const int t  = threadIdx.x;
    const int bb = blockIdx.y;
    const int t0 = blockIdx.x * 64;

#pragma unroll
    for (int it = 0; it < 2; ++it) {
        int lin = t + it * 256;
        int tok = lin >> 3;
        int d0  = (lin & 7) * 8;
        short8v v8 = {0, 0, 0, 0, 0, 0, 0, 0};
        if (t0 + tok < TDIM)
            v8 = *(const short8v*)&vb[((size_t)bb * TDIM + t0 + tok) * 64 + d0];
        union { short8v v; unsigned short s[8]; } u; u.v = v8;
#pragma unroll
        for (int j = 0; j < 8; ++j) tile[d0 + j][tok] = u.s[j];
    }
    __syncthreads();

    const int dh = t >> 2;
    const int ch = t & 3;
    short8v o0 = *(const short8v*)&tile[dh][ch * 16];
    short8v o1 = *(const short8v*)&tile[dh][ch * 16 + 8];
    size_t dst = ((size_t)bb * 64 + dh) * VTLD + t0 + ch * 16;
    *(short8v*)&vT[dst]     = o0;
    *(short8v*)&vT[dst + 8] = o1;
}

// ---------------------------------------------------------------------------
// Kernel 2: MFMA flash attention (unchanged from round 8/10).
// ---------------------------------------------------------------------------
__global__ __launch_bounds__(256) void attn_mfma_kernel(
    const unsigned short* __restrict__ qb, const unsigned short* __restrict__ kb,
    const unsigned short* __restrict__ vT,
    const float* __restrict__ a8, const float* __restrict__ isx,
    const float* __restrict__ isy, float* __restrict__ out)
{
    __shared__ unsigned short Ks[2][64][LDP];
    __shared__ unsigned short Vt[2][64][LDP];   // [dh][key]
    __shared__ unsigned short Pt[4][16][LDP];   // per-wave [q][key]

    const int t  = threadIdx.x;
    const int wv = t >> 6;
    const int ln = t & 63;
    const int lq = ln >> 4;
    const int lr = ln & 15;
    const int bb = blockIdx.y;
    const int q0 = blockIdx.x * 64;

    const int qrow = min(q0 + wv * 16 + lr, TDIM - 1);
    const size_t qbase = ((size_t)bb * TDIM + qrow) * 64;
    const short8v aq0 = *(const short8v*)&qb[qbase + lq * 8];
    const short8v aq1 = *(const short8v*)&qb[qbase + 32 + lq * 8];

    float a8q[4], sxq[4], syq[4], qpy[4], qpx[4];
    bool  hasS[4];
#pragma unroll
    for (int reg = 0; reg < 4; ++reg) {
        int qg = q0 + wv * 16 + lq * 4 + reg;
        hasS[reg] = false;
        a8q[reg] = 0.f; sxq[reg] = 0.f; syq[reg] = 0.f; qpy[reg] = 0.f; qpx[reg] = 0.f;
        if (qg >= 1 && qg < TDIM) {
            int qp = qg - 1;
            hasS[reg] = true;
            a8q[reg] = a8 [bb * TPATCH + qp];
            sxq[reg] = isx[bb * TPATCH + qp];
            syq[reg] = isy[bb * TPATCH + qp];
            qpy[reg] = (float)(qp >> 5);
            qpx[reg] = (float)(qp & 31);
        }
    }

    float m[4]  = {-1e30f, -1e30f, -1e30f, -1e30f};
    float l[4]  = {0.f, 0.f, 0.f, 0.f};
    f32x4 oacc[4];
#pragma unroll
    for (int ni = 0; ni < 4; ++ni) oacc[ni] = (f32x4){0.f, 0.f, 0.f, 0.f};

    const int sk_row = t >> 3;
    const int sk_d0  = (t & 7) * 8;
    short8v rk[2], rv[2];

#define ALOAD(KT0)                                                             \
    do {                                                                       \
        _Pragma("unroll") for (int it = 0; it < 2; ++it) {                     \
            int key = sk_row + 32 * it;                                        \
            int kg  = (KT0) + key;                                             \
            rk[it] = (kg < TDIM)                                               \
                ? *(const short8v*)&kb[((size_t)bb * TDIM + kg) * 64 + sk_d0]  \
                : (short8v){0, 0, 0, 0, 0, 0, 0, 0};                           \
            rv[it] = *(const short8v*)&vT[((size_t)bb * 64 + key) * VTLD +     \
                                          (KT0) + sk_d0];                      \
        }                                                                      \
    } while (0)

#define ASTORE(BUF)                                                            \
    do {                                                                       \
        _Pragma("unroll") for (int it = 0; it < 2; ++it) {                     \
            *(short8v*)&Ks[BUF][sk_row + 32 * it][sk_d0] = rk[it];             \
            *(short8v*)&Vt[BUF][sk_row + 32 * it][sk_d0] = rv[it];             \
        }                                                                      \
    } while (0)

    ALOAD(0);
    ASTORE(0);
    wg_barrier();

    for (int tile = 0; tile < NTILES; ++tile) {
        const int kt0 = tile * 64;
        const int buf = tile & 1;
        if (tile + 1 < NTILES) ALOAD(kt0 + 64);

        f32x4 sac[4];
#pragma unroll
        for (int ni = 0; ni < 4; ++ni) sac[ni] = (f32x4){0.f, 0.f, 0.f, 0.f};
#pragma unroll
        for (int ni = 0; ni < 4; ++ni) {
            short8v b0 = *(const short8v*)&Ks[buf][16 * ni + lr][lq * 8];
            short8v b1 = *(const short8v*)&Ks[buf][16 * ni + lr][32 + lq * 8];
            sac[ni] = __builtin_amdgcn_mfma_f32_16x16x32_bf16(aq0, b0, sac[ni], 0, 0, 0);
            sac[ni] = __builtin_amdgcn_mfma_f32_16x16x32_bf16(aq1, b1, sac[ni], 0, 0, 0);
        }

#pragma unroll
        for (int ni = 0; ni < 4; ++ni) {
            int key = kt0 + 16 * ni + lr;
            int kp  = key - 1;
            float ky = (float)(kp >> 5);
            float kx = (float)(kp & 31);
            bool kvalid = (key >= 1) && (key < TDIM);
#pragma unroll
            for (int reg = 0; reg < 4; ++reg) {
                float z = sac[ni][reg] * (1.f / SCALE);
                if (kvalid && hasS[reg]) {
                    float dy = qpy[reg] - ky;
                    float dx = qpx[reg] - kx;
                    z += a8q[reg] * __expf(-(dx * dx * sxq[reg] + dy * dy * syq[reg]));
                }
                if (key >= TDIM) z = -1e30f;
                sac[ni][reg] = z;
            }
        }

        float scf[4];
#pragma unroll
        for (int reg = 0; reg < 4; ++reg) {
            float mx = fmaxf(fmaxf(sac[0][reg], sac[1][reg]),
                             fmaxf(sac[2][reg], sac[3][reg]));
            mx = red16_max(mx);
            float mn = fmaxf(m[reg], mx);
            scf[reg] = __expf(m[reg] - mn);
            m[reg] = mn;
            float ts = 0.f;
#pragma unroll
            for (int ni = 0; ni < 4; ++ni) {
                float pp = __expf(sac[ni][reg] - mn);
                sac[ni][reg] = pp;
                ts += pp;
            }
            ts = red16_sum(ts);
            l[reg] = l[reg] * scf[reg] + ts;
        }
#pragma unroll
        for (int ni = 0; ni < 4; ++ni)
#pragma unroll
            for (int reg = 0; reg < 4; ++reg)
                oacc[ni][reg] *= scf[reg];

#pragma unroll
        for (int ni = 0; ni < 4; ++ni)
#pragma unroll
            for (int reg = 0; reg < 4; ++reg)
                Pt[wv][lq * 4 + reg][16 * ni + lr] = f2bf(sac[ni][reg]);

#pragma unroll
        for (int ks = 0; ks < 2; ++ks) {
            short8v pa = *(const short8v*)&Pt[wv][lr][ks * 32 + lq * 8];
#pragma unroll
            for (int ni = 0; ni < 4; ++ni) {
                short8v bv = *(const short8v*)&Vt[buf][16 * ni + lr][ks * 32 + lq * 8];
                oacc[ni] = __builtin_amdgcn_mfma_f32_16x16x32_bf16(pa, bv, oacc[ni], 0, 0, 0);
            }
        }

        if (tile + 1 < NTILES) ASTORE(buf ^ 1);
        wg_barrier();
    }
#undef ALOAD
#undef ASTORE

#pragma unroll
    for (int reg = 0; reg < 4; ++reg) {
        int qg = q0 + wv * 16 + lq * 4 + reg;
        if (qg < TDIM) {
            float rl = 1.f / l[reg];
#pragma unroll
            for (int ni = 0; ni < 4; ++ni)
                out[((size_t)bb * TDIM + qg) * 64 + 16 * ni + lr] = oacc[ni][reg] * rl;
        }
    }
}

extern "C" void kernel_launch(void* const* d_in, const int* in_sizes, int n_in,
                              void* d_out, int out_size, void* d_ws, size_t ws_size,
                              hipStream_t stream)
{
    const float* x    = (const float*)d_in[0];
    const float* Wq   = (const float*)d_in[1];
    const float* Wk   = (const float*)d_in[2];
    const float* Wv   = (const float*)d_in[3];
    const float* gq   = (const float*)d_in[4];
    const float* bq   = (const float*)d_in[5];
    const float* gk   = (const float*)d_in[6];
    const float* bk   = (const float*)d_in[7];
    const float* Wsig = (const float*)d_in[8];
    const float* bsig = (const float*)d_in[9];
    const float* Wa   = (const float*)d_in[10];
    const float* ba   = (const float*)d_in[11];
    float* out = (float*)d_out;

    // ---- workspace layout ----
    char* w = (char*)d_ws;
    const size_t NQ = (size_t)NROW * 64;
    unsigned short* qb = (unsigned short*)w;   w += NQ * 2;
    unsigned short* kb = (unsigned short*)w;   w += NQ * 2;
    unsigned short* vb = (unsigned short*)w;   w += NQ * 2;
    unsigned short* vT = (unsigned short*)w;   w += (size_t)BDIM * 64 * VTLD * 2;
    float* a8  = (float*)w;                    w += (size_t)BDIM * TPATCH * 4;
    float* isx = (float*)w;                    w += (size_t)BDIM * TPATCH * 4;
    float* isy = (float*)w;                    w += (size_t)BDIM * TPATCH * 4;
    unsigned short* wT = (unsigned short*)w;   w += (size_t)192 * DDIM * 2;

    hipLaunchKernelGGL(prep_w_kernel, dim3(192), dim3(256), 0, stream,
                       Wq, Wk, Wv, wT);

    const int nblk1 = (NROW + 63) / 64;   // 513 blocks of 64 rows
    hipLaunchKernelGGL(qkv_bstat_kernel, dim3(nblk1), dim3(256), 0, stream,
                       x, wT, gq, bq, gk, bk, Wsig, bsig, Wa, ba,
                       qb, kb, vb, a8, isx, isy);

    hipLaunchKernelGGL(vtrans_kernel, dim3(17, BDIM), dim3(256), 0, stream,
                       vb, vT);

    hipLaunchKernelGGL(attn_mfma_kernel, dim3(17, BDIM), dim3(256), 0, stream,
                       qb, kb, vT, a8, isx, isy, out);
}

// Round 12
// 95.282 us; speedup vs baseline: 1.3025x; 1.3025x over previous
//
#include <hip/hip_runtime.h>
#include <hip/hip_bf16.h>
#include <math.h>

#define BDIM 32
#define TDIM 1025
#define DDIM 768
#define GRIDW 32
#define TPATCH 1024
#define SCALE 8.0f
#define EPSLN 1e-5f
#define NROW (BDIM * TDIM)   // 32800
#define VTLD 1088            // vT row stride (elements, 16B-aligned)
#define LDP  72              // LDS row stride for attn tiles
#define LDQ  40              // LDS row stride for qkv tiles (BK=32)
#define NTILES 17

typedef __attribute__((ext_vector_type(8))) short short8v;   // 8 bf16 (4 VGPRs)
typedef __attribute__((ext_vector_type(4))) float f32x4;     // MFMA C/D frag

__device__ __forceinline__ unsigned short f2bf(float f) {
    unsigned int u = __float_as_uint(f);
    u += 0x7FFFu + ((u >> 16) & 1u);      // round-to-nearest-even
    return (unsigned short)(u >> 16);
}

__device__ __forceinline__ short8v pack8(float4 a, float4 b) {
    union { short8v v; unsigned short s[8]; } u;
    u.s[0] = f2bf(a.x); u.s[1] = f2bf(a.y); u.s[2] = f2bf(a.z); u.s[3] = f2bf(a.w);
    u.s[4] = f2bf(b.x); u.s[5] = f2bf(b.y); u.s[6] = f2bf(b.z); u.s[7] = f2bf(b.w);
    return u.v;
}

// Raw workgroup barrier (no vmcnt(0) drain) — used ONLY in attn, where it is
// measured-good. qkv uses plain __syncthreads (its measured-best variant).
__device__ __forceinline__ void wg_barrier() {
    asm volatile("s_waitcnt lgkmcnt(0)" ::: "memory");
    __builtin_amdgcn_s_barrier();
    __builtin_amdgcn_sched_barrier(0);
}

// ---- 16-lane DPP reductions (attn only) ----
template<int CTRL>
__device__ __forceinline__ float dpp_f(float x) {
    return __int_as_float(__builtin_amdgcn_update_dpp(
        __float_as_int(x), __float_as_int(x), CTRL, 0xF, 0xF, true));
}
__device__ __forceinline__ float red16_max(float x) {
    x = fmaxf(x, dpp_f<0xB1>(x));
    x = fmaxf(x, dpp_f<0x4E>(x));
    x = fmaxf(x, dpp_f<0x124>(x));
    x = fmaxf(x, dpp_f<0x128>(x));
    return x;
}
__device__ __forceinline__ float red16_sum(float x) {
    x += dpp_f<0xB1>(x);
    x += dpp_f<0x4E>(x);
    x += dpp_f<0x124>(x);
    x += dpp_f<0x128>(x);
    return x;
}

// ---------------------------------------------------------------------------
// Kernel 0: W -> bf16, transposed: wT[c][k], c = 0..191 (q|k|v), k = 0..767
// ---------------------------------------------------------------------------
__global__ __launch_bounds__(256) void prep_w_kernel(
    const float* __restrict__ Wq, const float* __restrict__ Wk,
    const float* __restrict__ Wv, unsigned short* __restrict__ wT)
{
    const int c = blockIdx.x;
    const float* W = (c < 64) ? Wq : (c < 128) ? Wk : Wv;
    const int cc = c & 63;
    for (int k = threadIdx.x; k < DDIM; k += 256)
        wT[(size_t)c * DDIM + k] = f2bf(W[(size_t)k * 64 + cc]);
}

// ---------------------------------------------------------------------------
// Kernel 1: MFMA QKV projection + fused LN + heads — R5-measured-best variant.
// 513 blocks x 4 waves; 64 rows x 192 cols; BK=32, 24 steps; double-buffered
// LDS; per step: STORE(regs->LDS buf) -> issue LOAD(ks+1) -> __syncthreads ->
// COMPUTE(buf). shfl_xor epilogue (DPP epilogue perturbed K-loop codegen).
// ---------------------------------------------------------------------------
__global__ __launch_bounds__(256) void qkv_tile_kernel(
    const float* __restrict__ x, const unsigned short* __restrict__ wT,
    const float* __restrict__ gq, const float* __restrict__ bq,
    const float* __restrict__ gk, const float* __restrict__ bk,
    const float* __restrict__ Wsig, const float* __restrict__ bsig,
    const float* __restrict__ Wa, const float* __restrict__ ba,
    unsigned short* __restrict__ qb, unsigned short* __restrict__ kb,
    unsigned short* __restrict__ vb,
    float* __restrict__ a8, float* __restrict__ isx, float* __restrict__ isy)
{
    __shared__ unsigned short As[2][64][LDQ];    // 10.2 KB
    __shared__ unsigned short Bs[2][192][LDQ];   // 30.7 KB

    const int t  = threadIdx.x;
    const int wv = t >> 6;
    const int ln = t & 63;
    const int lq = ln >> 4;
    const int lr = ln & 15;
    const int tok0 = blockIdx.x * 64;           // flat row (b*TDIM + ti)

    const int arow = t >> 2;
    const int aseg = t & 3;
    const float* aptr = x + (size_t)min(tok0 + arow, NROW - 1) * DDIM + aseg * 8;
    const int brow = t >> 2;
    const int bseg = t & 3;

    f32x4 acc[12];
#pragma unroll
    for (int ni = 0; ni < 12; ++ni) acc[ni] = (f32x4){0.f, 0.f, 0.f, 0.f};

    float4 ra0, ra1;
    short8v rb0, rb1, rb2;

    // prologue: load k-step 0
    ra0 = *(const float4*)(aptr + 0);
    ra1 = *(const float4*)(aptr + 4);
    rb0 = *(const short8v*)&wT[(size_t)(brow +   0) * DDIM + bseg * 8];
    rb1 = *(const short8v*)&wT[(size_t)(brow +  64) * DDIM + bseg * 8];
    rb2 = *(const short8v*)&wT[(size_t)(brow + 128) * DDIM + bseg * 8];

#pragma unroll
    for (int ks = 0; ks < 24; ++ks) {
        const int buf = ks & 1;
        // stage regs -> LDS (waits on loads issued last iter)
        *(short8v*)&As[buf][arow][aseg * 8]        = pack8(ra0, ra1);
        *(short8v*)&Bs[buf][brow +   0][bseg * 8]  = rb0;
        *(short8v*)&Bs[buf][brow +  64][bseg * 8]  = rb1;
        *(short8v*)&Bs[buf][brow + 128][bseg * 8]  = rb2;
        // issue next-step global loads
        if (ks + 1 < 24) {
            const int k0 = (ks + 1) * 32;
            ra0 = *(const float4*)(aptr + k0 + 0);
            ra1 = *(const float4*)(aptr + k0 + 4);
            rb0 = *(const short8v*)&wT[(size_t)(brow +   0) * DDIM + k0 + bseg * 8];
            rb1 = *(const short8v*)&wT[(size_t)(brow +  64) * DDIM + k0 + bseg * 8];
            rb2 = *(const short8v*)&wT[(size_t)(brow + 128) * DDIM + k0 + bseg * 8];
        }
        __syncthreads();
        short8v af = *(const short8v*)&As[buf][wv * 16 + lr][lq * 8];
#pragma unroll
        for (int ni = 0; ni < 12; ++ni) {
            short8v bf = *(const short8v*)&Bs[buf][16 * ni + lr][lq * 8];
            acc[ni] = __builtin_amdgcn_mfma_f32_16x16x32_bf16(af, bf, acc[ni], 0, 0, 0);
        }
    }

    // ---- epilogue: LN(q), LN(k), alpha/sigma head, writes (shfl_xor) ----
    float gqv[4], bqv[4], gkv[4], bkv[4], wav[4], ws0[4], ws1[4];
#pragma unroll
    for (int ni = 0; ni < 4; ++ni) {
        int c = lr + 16 * ni;
        gqv[ni] = gq[c]; bqv[ni] = bq[c];
        gkv[ni] = gk[c]; bkv[ni] = bk[c];
        wav[ni] = Wa[c];
        ws0[ni] = Wsig[2 * c];
        ws1[ni] = Wsig[2 * c + 1];
    }
    const float ba0 = ba[0], bs0 = bsig[0], bs1 = bsig[1];

#pragma unroll
    for (int reg = 0; reg < 4; ++reg) {
        const int tokr = tok0 + wv * 16 + lq * 4 + reg;

        float s1 = 0.f, s2 = 0.f;
#pragma unroll
        for (int ni = 0; ni < 4; ++ni) {
            float v = acc[ni][reg];
            s1 += v; s2 += v * v;
        }
#pragma unroll
        for (int off = 1; off < 16; off <<= 1) {
            s1 += __shfl_xor(s1, off);
            s2 += __shfl_xor(s2, off);
        }
        float mean = s1 * (1.f / 64.f);
        float var  = s2 * (1.f / 64.f) - mean * mean;
        float rstd = rsqrtf(var + EPSLN);
        float qn[4];
#pragma unroll
        for (int ni = 0; ni < 4; ++ni)
            qn[ni] = (acc[ni][reg] - mean) * rstd * gqv[ni] + bqv[ni];

        s1 = 0.f; s2 = 0.f;
#pragma unroll
        for (int ni = 0; ni < 4; ++ni) {
            float v = acc[4 + ni][reg];
            s1 += v; s2 += v * v;
        }
#pragma unroll
        for (int off = 1; off < 16; off <<= 1) {
            s1 += __shfl_xor(s1, off);
            s2 += __shfl_xor(s2, off);
        }
        mean = s1 * (1.f / 64.f);
        var  = s2 * (1.f / 64.f) - mean * mean;
        rstd = rsqrtf(var + EPSLN);
        float kn[4];
#pragma unroll
        for (int ni = 0; ni < 4; ++ni)
            kn[ni] = (acc[4 + ni][reg] - mean) * rstd * gkv[ni] + bkv[ni];

        float da = 0.f, d0 = 0.f, d1 = 0.f;
#pragma unroll
        for (int ni = 0; ni < 4; ++ni) {
            da += qn[ni] * wav[ni];
            d0 += qn[ni] * ws0[ni];
            d1 += qn[ni] * ws1[ni];
        }
#pragma unroll
        for (int off = 1; off < 16; off <<= 1) {
            da += __shfl_xor(da, off);
            d0 += __shfl_xor(d0, off);
            d1 += __shfl_xor(d1, off);
        }

        if (tokr < NROW) {
            size_t base = (size_t)tokr * 64;
            int bidx = tokr / TDIM;
            int ti   = tokr - bidx * TDIM;
#pragma unroll
            for (int ni = 0; ni < 4; ++ni) {
                int c = lr + 16 * ni;
                qb[base + c] = f2bf(qn[ni]);
                kb[base + c] = f2bf(kn[ni]);
                vb[base + c] = f2bf(acc[8 + ni][reg]);
            }
            if (lr == 0 && ti >= 1) {
                int p = bidx * TPATCH + ti - 1;
                float av = da + ba0;
                float sp = (av > 20.f) ? av : log1pf(__expf(av));
                a8[p] = sp * (1.f / SCALE);
                float sx = 1.f / (1.f + __expf(-(d0 + bs0)));
                float sy = 1.f / (1.f + __expf(-(d1 + bs1)));
                isx[p] = 0.5f / (sx * sx);
                isy[p] = 0.5f / (sy * sy);
            }
        }
    }
}

// ---------------------------------------------------------------------------
// Kernel 1b: vb [token][dh] -> vT [b][dh][token] via LDS transpose.
// ---------------------------------------------------------------------------
__global__ __launch_bounds__(256) void vtrans_kernel(
    const unsigned short* __restrict__ vb, unsigned short* __restrict__ vT)
{
    __shared__ unsigned short tile[64][LDP];   // [dh][token]
    const int t  = threadIdx.x;
    const int bb = blockIdx.y;
    const int t0 = blockIdx.x * 64;

#pragma unroll
    for (int it = 0; it < 2; ++it) {
        int lin = t + it * 256;
        int tok = lin >> 3;
        int d0  = (lin & 7) * 8;
        short8v v8 = {0, 0, 0, 0, 0, 0, 0, 0};
        if (t0 + tok < TDIM)
            v8 = *(const short8v*)&vb[((size_t)bb * TDIM + t0 + tok) * 64 + d0];
        union { short8v v; unsigned short s[8]; } u; u.v = v8;
#pragma unroll
        for (int j = 0; j < 8; ++j) tile[d0 + j][tok] = u.s[j];
    }
    __syncthreads();

    const int dh = t >> 2;
    const int ch = t & 3;
    short8v o0 = *(const short8v*)&tile[dh][ch * 16];
    short8v o1 = *(const short8v*)&tile[dh][ch * 16 + 8];
    size_t dst = ((size_t)bb * 64 + dh) * VTLD + t0 + ch * 16;
    *(short8v*)&vT[dst]     = o0;
    *(short8v*)&vT[dst + 8] = o1;
}

// ---------------------------------------------------------------------------
// Kernel 2: MFMA flash attention (R8-measured-best: raw barriers, dbuf K/V,
// issue-early/write-late, DPP softmax, Q direct from global).
// ---------------------------------------------------------------------------
__global__ __launch_bounds__(256) void attn_mfma_kernel(
    const unsigned short* __restrict__ qb, const unsigned short* __restrict__ kb,
    const unsigned short* __restrict__ vT,
    const float* __restrict__ a8, const float* __restrict__ isx,
    const float* __restrict__ isy, float* __restrict__ out)
{
    __shared__ unsigned short Ks[2][64][LDP];
    __shared__ unsigned short Vt[2][64][LDP];   // [dh][key]
    __shared__ unsigned short Pt[4][16][LDP];   // per-wave [q][key]

    const int t  = threadIdx.x;
    const int wv = t >> 6;
    const int ln = t & 63;
    const int lq = ln >> 4;
    const int lr = ln & 15;
    const int bb = blockIdx.y;
    const int q0 = blockIdx.x * 64;

    const int qrow = min(q0 + wv * 16 + lr, TDIM - 1);
    const size_t qbase = ((size_t)bb * TDIM + qrow) * 64;
    const short8v aq0 = *(const short8v*)&qb[qbase + lq * 8];
    const short8v aq1 = *(const short8v*)&qb[qbase + 32 + lq * 8];

    float a8q[4], sxq[4], syq[4], qpy[4], qpx[4];
    bool  hasS[4];
#pragma unroll
    for (int reg = 0; reg < 4; ++reg) {
        int qg = q0 + wv * 16 + lq * 4 + reg;
        hasS[reg] = false;
        a8q[reg] = 0.f; sxq[reg] = 0.f; syq[reg] = 0.f; qpy[reg] = 0.f; qpx[reg] = 0.f;
        if (qg >= 1 && qg < TDIM) {
            int qp = qg - 1;
            hasS[reg] = true;
            a8q[reg] = a8 [bb * TPATCH + qp];
            sxq[reg] = isx[bb * TPATCH + qp];
            syq[reg] = isy[bb * TPATCH + qp];
            qpy[reg] = (float)(qp >> 5);
            qpx[reg] = (float)(qp & 31);
        }
    }

    float m[4]  = {-1e30f, -1e30f, -1e30f, -1e30f};
    float l[4]  = {0.f, 0.f, 0.f, 0.f};
    f32x4 oacc[4];
#pragma unroll
    for (int ni = 0; ni < 4; ++ni) oacc[ni] = (f32x4){0.f, 0.f, 0.f, 0.f};

    const int sk_row = t >> 3;
    const int sk_d0  = (t & 7) * 8;
    short8v rk[2], rv[2];

#define ALOAD(KT0)                                                             \
    do {                                                                       \
        _Pragma("unroll") for (int it = 0; it < 2; ++it) {                     \
            int key = sk_row + 32 * it;                                        \
            int kg  = (KT0) + key;                                             \
            rk[it] = (kg < TDIM)                                               \
                ? *(const short8v*)&kb[((size_t)bb * TDIM + kg) * 64 + sk_d0]  \
                : (short8v){0, 0, 0, 0, 0, 0, 0, 0};                           \
            rv[it] = *(const short8v*)&vT[((size_t)bb * 64 + key) * VTLD +     \
                                          (KT0) + sk_d0];                      \
        }                                                                      \
    } while (0)

#define ASTORE(BUF)                                                            \
    do {                                                                       \
        _Pragma("unroll") for (int it = 0; it < 2; ++it) {                     \
            *(short8v*)&Ks[BUF][sk_row + 32 * it][sk_d0] = rk[it];             \
            *(short8v*)&Vt[BUF][sk_row + 32 * it][sk_d0] = rv[it];             \
        }                                                                      \
    } while (0)

    ALOAD(0);
    ASTORE(0);
    wg_barrier();

    for (int tile = 0; tile < NTILES; ++tile) {
        const int kt0 = tile * 64;
        const int buf = tile & 1;
        if (tile + 1 < NTILES) ALOAD(kt0 + 64);

        f32x4 sac[4];
#pragma unroll
        for (int ni = 0; ni < 4; ++ni) sac[ni] = (f32x4){0.f, 0.f, 0.f, 0.f};
#pragma unroll
        for (int ni = 0; ni < 4; ++ni) {
            short8v b0 = *(const short8v*)&Ks[buf][16 * ni + lr][lq * 8];
            short8v b1 = *(const short8v*)&Ks[buf][16 * ni + lr][32 + lq * 8];
            sac[ni] = __builtin_amdgcn_mfma_f32_16x16x32_bf16(aq0, b0, sac[ni], 0, 0, 0);
            sac[ni] = __builtin_amdgcn_mfma_f32_16x16x32_bf16(aq1, b1, sac[ni], 0, 0, 0);
        }

#pragma unroll
        for (int ni = 0; ni < 4; ++ni) {
            int key = kt0 + 16 * ni + lr;
            int kp  = key - 1;
            float ky = (float)(kp >> 5);
            float kx = (float)(kp & 31);
            bool kvalid = (key >= 1) && (key < TDIM);
#pragma unroll
            for (int reg = 0; reg < 4; ++reg) {
                float z = sac[ni][reg] * (1.f / SCALE);
                if (kvalid && hasS[reg]) {
                    float dy = qpy[reg] - ky;
                    float dx = qpx[reg] - kx;
                    z += a8q[reg] * __expf(-(dx * dx * sxq[reg] + dy * dy * syq[reg]));
                }
                if (key >= TDIM) z = -1e30f;
                sac[ni][reg] = z;
            }
        }

        float scf[4];
#pragma unroll
        for (int reg = 0; reg < 4; ++reg) {
            float mx = fmaxf(fmaxf(sac[0][reg], sac[1][reg]),
                             fmaxf(sac[2][reg], sac[3][reg]));
            mx = red16_max(mx);
            float mn = fmaxf(m[reg], mx);
            scf[reg] = __expf(m[reg] - mn);
            m[reg] = mn;
            float ts = 0.f;
#pragma unroll
            for (int ni = 0; ni < 4; ++ni) {
                float pp = __expf(sac[ni][reg] - mn);
                sac[ni][reg] = pp;
                ts += pp;
            }
            ts = red16_sum(ts);
            l[reg] = l[reg] * scf[reg] + ts;
        }
#pragma unroll
        for (int ni = 0; ni < 4; ++ni)
#pragma unroll
            for (int reg = 0; reg < 4; ++reg)
                oacc[ni][reg] *= scf[reg];

#pragma unroll
        for (int ni = 0; ni < 4; ++ni)
#pragma unroll
            for (int reg = 0; reg < 4; ++reg)
                Pt[wv][lq * 4 + reg][16 * ni + lr] = f2bf(sac[ni][reg]);

#pragma unroll
        for (int ks = 0; ks < 2; ++ks) {
            short8v pa = *(const short8v*)&Pt[wv][lr][ks * 32 + lq * 8];
#pragma unroll
            for (int ni = 0; ni < 4; ++ni) {
                short8v bv = *(const short8v*)&Vt[buf][16 * ni + lr][ks * 32 + lq * 8];
                oacc[ni] = __builtin_amdgcn_mfma_f32_16x16x32_bf16(pa, bv, oacc[ni], 0, 0, 0);
            }
        }

        if (tile + 1 < NTILES) ASTORE(buf ^ 1);
        wg_barrier();
    }
#undef ALOAD
#undef ASTORE

#pragma unroll
    for (int reg = 0; reg < 4; ++reg) {
        int qg = q0 + wv * 16 + lq * 4 + reg;
        if (qg < TDIM) {
            float rl = 1.f / l[reg];
#pragma unroll
            for (int ni = 0; ni < 4; ++ni)
                out[((size_t)bb * TDIM + qg) * 64 + 16 * ni + lr] = oacc[ni][reg] * rl;
        }
    }
}

extern "C" void kernel_launch(void* const* d_in, const int* in_sizes, int n_in,
                              void* d_out, int out_size, void* d_ws, size_t ws_size,
                              hipStream_t stream)
{
    const float* x    = (const float*)d_in[0];
    const float* Wq   = (const float*)d_in[1];
    const float* Wk   = (const float*)d_in[2];
    const float* Wv   = (const float*)d_in[3];
    const float* gq   = (const float*)d_in[4];
    const float* bq   = (const float*)d_in[5];
    const float* gk   = (const float*)d_in[6];
    const float* bk   = (const float*)d_in[7];
    const float* Wsig = (const float*)d_in[8];
    const float* bsig = (const float*)d_in[9];
    const float* Wa   = (const float*)d_in[10];
    const float* ba   = (const float*)d_in[11];
    float* out = (float*)d_out;

    // ---- workspace layout ----
    char* w = (char*)d_ws;
    const size_t NQ = (size_t)NROW * 64;
    unsigned short* qb = (unsigned short*)w;   w += NQ * 2;
    unsigned short* kb = (unsigned short*)w;   w += NQ * 2;
    unsigned short* vb = (unsigned short*)w;   w += NQ * 2;
    unsigned short* vT = (unsigned short*)w;   w += (size_t)BDIM * 64 * VTLD * 2;
    float* a8  = (float*)w;                    w += (size_t)BDIM * TPATCH * 4;
    float* isx = (float*)w;                    w += (size_t)BDIM * TPATCH * 4;
    float* isy = (float*)w;                    w += (size_t)BDIM * TPATCH * 4;
    unsigned short* wT = (unsigned short*)w;   w += (size_t)192 * DDIM * 2;

    hipLaunchKernelGGL(prep_w_kernel, dim3(192), dim3(256), 0, stream,
                       Wq, Wk, Wv, wT);

    const int nblk1 = (NROW + 63) / 64;   // 513
    hipLaunchKernelGGL(qkv_tile_kernel, dim3(nblk1), dim3(256), 0, stream,
                       x, wT, gq, bq, gk, bk, Wsig, bsig, Wa, ba,
                       qb, kb, vb, a8, isx, isy);

    hipLaunchKernelGGL(vtrans_kernel, dim3(17, BDIM), dim3(256), 0, stream,
                       vb, vT);

    hipLaunchKernelGGL(attn_mfma_kernel, dim3(17, BDIM), dim3(256), 0, stream,
                       qb, kb, vT, a8, isx, isy, out);
}